// Round 9
// baseline (4881.727 us; speedup 1.0000x reference)
//
#include <hip/hip_runtime.h>

#define BATCH 64
#define SEQ 8192
#define RDIM 80
#define CSTEP 8
#define NCHUNK (SEQ / CSTEP)       // 1024 chunks, 1 barrier each
#define RSLOTS 176                 // ring capacity: max tau 168 + chunk 8
#define SLOT_B (RDIM * 4)          // 320 B per slot
#define RING_B (RSLOTS * SLOT_B)   // 56320 B
#define CHUNK_B (CSTEP * SLOT_B)   // 2560 B advance per chunk

typedef float v2f __attribute__((ext_vector_type(2)));

__device__ __forceinline__ float fast_tanh(float z) {
    // tanh(z) = 1 - 2/(exp(2z)+1); exact saturation, abs err ~1e-7
    float e = __expf(2.0f * z);
    return 1.0f - 2.0f / (e + 1.0f);
}

// v + (v from lane ^ pattern) via DPP quad_perm (pure VALU)
// 0xB1 = quad_perm(1,0,3,2) -> xor 1 ; 0x4E = quad_perm(2,3,0,1) -> xor 2
template <int CTRL>
__device__ __forceinline__ float dpp_xor_add(float v) {
    int o = __builtin_amdgcn_mov_dpp(__float_as_int(v), CTRL, 0xF, 0xF, true);
    return v + __int_as_float(o);
}

// Single batch per block (64 blocks on 256 CUs), 256 thr = 4 waves = 1/SIMD.
// tau=4 is FOLDED INTO the recurrence wave via a 4-deep in-register history of
// the broadcast h-slice -> min tap delay becomes 24 -> 8-step chunks are
// race-free (taps write slots >= 8c+16 while rec reads 8c..8c+7) -> barriers
// drop 4096 -> 1024. Taps: one matrix per wave {24,96,168}, rec-style layout.
__global__ __attribute__((amdgpu_flat_work_group_size(256, 256),
                          amdgpu_waves_per_eu(1, 1)))
void reservoir_kernel(const float* __restrict__ x,
                      const float* __restrict__ W_in,
                      const float* __restrict__ W_fb,
                      const float* __restrict__ bias,
                      float* __restrict__ out) {
    // ring[slot][i]: accumulated far-tap contributions for step s = slot (mod 176)
    __shared__ __align__(16) float ring[RSLOTS * RDIM];        // 56320 B
    // h_hist: two chunk-halves of 8 steps x 80; rec writes (c&1), taps read ((c-1)&1)
    __shared__ __align__(16) float h_hist[2 * CSTEP * RDIM];   // 5120 B

    const int b    = blockIdx.x;
    const int t    = threadIdx.x;
    const int wid  = t >> 6;   // 0 = recurrence(W1+W4), 1..3 = taps tau {24,96,168}
    const int lane = t & 63;

    for (int i = t; i < RSLOTS * RDIM; i += 256) ring[i] = 0.0f;
    for (int i = t; i < 2 * CSTEP * RDIM; i += 256) h_hist[i] = 0.0f;

    const float* xb   = x + (size_t)b * SEQ;
    float*       outb = out + (size_t)b * (size_t)SEQ * RDIM;

    // ---- common layout (rec AND taps): quad q owns rows 5q..5q+4;
    //      lane (q,sub) covers j in [20*sub, 20*sub+20); quad all-reduce via DPP.
    const int q = lane >> 2, sub = lane & 3;
    const int rowA = 5 * q + sub;    // owned by this lane
    const int rowB = 5 * q + 4;      // owned by sub==0 lane

    v2f wm[50];   // this wave's matrix slice: rec=W_fb[0] (tau1), taps=W_fb[wid+1]
    {
        const int km = (wid == 0) ? 0 : (wid + 1);
        #pragma unroll
        for (int r = 0; r < 5; ++r) {
            const float* src = W_fb + (size_t)km * RDIM * RDIM
                                    + (size_t)(5 * q + r) * RDIM + 20 * sub;
            #pragma unroll
            for (int j4 = 0; j4 < 5; ++j4) {
                float4 v = ((const float4*)src)[j4];
                wm[r * 10 + 2 * j4 + 0] = (v2f){v.x, v.y};
                wm[r * 10 + 2 * j4 + 1] = (v2f){v.z, v.w};
            }
        }
    }

    // ---- rec-only state
    v2f w4[50];            // W_fb[1] (tau=4) slice
    float4 hist[4][5];     // rolling h-slice history: hist[s&3] = slice(h_s); W1
                           // reads hist[(s-1)&3], W4 reads hist[(s-4)&3]=hist[s&3]
    float winA = 0.f, winB = 0.f, bA = 0.f, bB = 0.f, hA = 0.f, hB = 0.f;
    float4 xc0 = {0,0,0,0}, xc1 = {0,0,0,0};
    int tap_base = 0;
    if (wid == 0) {
        #pragma unroll
        for (int r = 0; r < 5; ++r) {
            const float* src = W_fb + (size_t)RDIM * RDIM
                                    + (size_t)(5 * q + r) * RDIM + 20 * sub;
            #pragma unroll
            for (int j4 = 0; j4 < 5; ++j4) {
                float4 v = ((const float4*)src)[j4];
                w4[r * 10 + 2 * j4 + 0] = (v2f){v.x, v.y};
                w4[r * 10 + 2 * j4 + 1] = (v2f){v.z, v.w};
            }
        }
        winA = W_in[rowA]; bA = bias[rowA];
        winB = W_in[rowB]; bB = bias[rowB];
        #pragma unroll
        for (int i = 0; i < 4; ++i)
            #pragma unroll
            for (int j = 0; j < 5; ++j) hist[i][j] = (float4){0.f, 0.f, 0.f, 0.f};
        xc0 = ((const float4*)xb)[0];      // x[0..3]
        xc1 = ((const float4*)xb)[1];      // x[4..7]
    } else {
        const int tau = (wid == 1) ? 24 : (wid == 2) ? 96 : 168;
        tap_base = tau * SLOT_B;           // slot for sp=0 target (first work at c=1)
    }
    int rec_base = 0;

    __syncthreads();   // full fence once; in-loop barriers are raw s_barrier

    for (int c = 0; c < NCHUNK; ++c) {
        if (wid == 0) {
            // ============ recurrence wave: steps 8c..8c+7 (W1 + folded W4) ============
            // hoist ring reads + retire (slots final: taps this chunk write >= 8c+16)
            float rg[8], rgB[8];
            float* rp = (float*)((char*)ring + rec_base);
            #pragma unroll
            for (int st = 0; st < 8; ++st) {
                rg[st] = rp[st * RDIM + rowA]; rp[st * RDIM + rowA] = 0.f;
                if (sub == 0) { rgB[st] = rp[st * RDIM + rowB]; rp[st * RDIM + rowB] = 0.f; }
            }
            // prefetch next chunk's x (16B aligned)
            float4 xn0 = xc0, xn1 = xc1;
            if (c + 1 < NCHUNK) {
                const float4* xp = (const float4*)(xb + (size_t)(c + 1) * CSTEP);
                xn0 = xp[0]; xn1 = xp[1];
            }
            float* hwp = h_hist + (c & 1) * (CSTEP * RDIM);

            #pragma unroll
            for (int st = 0; st < 8; ++st) {
                const int h4 = st & 3;         // slice(h_{s-4}) — overwritten below by h_s
                const int h1 = (st + 3) & 3;   // slice(h_{s-1}) — readback from prev step
                v2f dd2[5];
                #pragma unroll
                for (int r = 0; r < 5; ++r) dd2[r] = (v2f){0.f, 0.f};
                // W4 block FIRST: register-only, hides the in-flight h_{s-1} readback
                #pragma unroll
                for (int r = 0; r < 5; ++r)
                    #pragma unroll
                    for (int j4 = 0; j4 < 5; ++j4) {
                        const v2f* hv = (const v2f*)&hist[h4][j4];
                        dd2[r] = __builtin_elementwise_fma(w4[r * 10 + 2 * j4 + 0], hv[0], dd2[r]);
                        dd2[r] = __builtin_elementwise_fma(w4[r * 10 + 2 * j4 + 1], hv[1], dd2[r]);
                    }
                // W1 block: uses the readback issued at end of previous step
                #pragma unroll
                for (int r = 0; r < 5; ++r)
                    #pragma unroll
                    for (int j4 = 0; j4 < 5; ++j4) {
                        const v2f* hv = (const v2f*)&hist[h1][j4];
                        dd2[r] = __builtin_elementwise_fma(wm[r * 10 + 2 * j4 + 0], hv[0], dd2[r]);
                        dd2[r] = __builtin_elementwise_fma(wm[r * 10 + 2 * j4 + 1], hv[1], dd2[r]);
                    }
                float dd[5];
                #pragma unroll
                for (int r = 0; r < 5; ++r) dd[r] = dd2[r].x + dd2[r].y;
                #pragma unroll
                for (int r = 0; r < 5; ++r) {
                    dd[r] = dpp_xor_add<0xB1>(dd[r]);
                    dd[r] = dpp_xor_add<0x4E>(dd[r]);
                }
                float dA = (sub == 0) ? dd[0] : (sub == 1) ? dd[1] : (sub == 2) ? dd[2] : dd[3];
                const float xs = (st == 0) ? xc0.x : (st == 1) ? xc0.y : (st == 2) ? xc0.z :
                                 (st == 3) ? xc0.w : (st == 4) ? xc1.x : (st == 5) ? xc1.y :
                                 (st == 6) ? xc1.z : xc1.w;
                float zA = dA + rg[st] + bA + xs * winA;
                hA = 0.7f * hA + 0.3f * fast_tanh(zA);
                if (sub == 0) {
                    float zB = dd[4] + rgB[st] + bB + xs * winB;
                    hB = 0.7f * hB + 0.3f * fast_tanh(zB);
                }
                // publish h_s (taps read next chunk; rec reads back its slice)
                hwp[st * RDIM + rowA] = hA;
                if (sub == 0) hwp[st * RDIM + rowB] = hB;
                // readback h_s slice DIRECTLY into the dead history slot hist[st&3]
                // (h_{s-4} consumed above; same-wave DS ordering; only rec writes hwp)
                {
                    const float4* hp = (const float4*)(hwp + st * RDIM + 20 * sub);
                    #pragma unroll
                    for (int j4 = 0; j4 < 5; ++j4) hist[h4][j4] = hp[j4];
                }
                // fire-and-forget output store (never read; no vmcnt drain)
                outb[(size_t)(c * CSTEP + st) * RDIM + rowA] = hA;
                if (sub == 0) outb[(size_t)(c * CSTEP + st) * RDIM + rowB] = hB;
            }
            xc0 = xn0; xc1 = xn1;
            rec_base += CHUNK_B; if (rec_base >= RING_B) rec_base -= RING_B;
        } else if (c > 0) {
            // ============ tap wave (one matrix): steps 8(c-1)..8(c-1)+7 ============
            const float* hrp = h_hist + ((c - 1) & 1) * (CSTEP * RDIM);
            float* trp = (float*)((char*)ring + tap_base);
            #pragma unroll
            for (int st = 0; st < 8; ++st) {
                float4 hv4[5];
                const float4* hp = (const float4*)(hrp + st * RDIM + 20 * sub);
                #pragma unroll
                for (int j4 = 0; j4 < 5; ++j4) hv4[j4] = hp[j4];
                v2f dd2[5];
                #pragma unroll
                for (int r = 0; r < 5; ++r) dd2[r] = (v2f){0.f, 0.f};
                #pragma unroll
                for (int r = 0; r < 5; ++r)
                    #pragma unroll
                    for (int j4 = 0; j4 < 5; ++j4) {
                        const v2f* hv = (const v2f*)&hv4[j4];
                        dd2[r] = __builtin_elementwise_fma(wm[r * 10 + 2 * j4 + 0], hv[0], dd2[r]);
                        dd2[r] = __builtin_elementwise_fma(wm[r * 10 + 2 * j4 + 1], hv[1], dd2[r]);
                    }
                float dd[5];
                #pragma unroll
                for (int r = 0; r < 5; ++r) dd[r] = dd2[r].x + dd2[r].y;
                #pragma unroll
                for (int r = 0; r < 5; ++r) {
                    dd[r] = dpp_xor_add<0xB1>(dd[r]);
                    dd[r] = dpp_xor_add<0x4E>(dd[r]);
                }
                float dA = (sub == 0) ? dd[0] : (sub == 1) ? dd[1] : (sub == 2) ? dd[2] : dd[3];
                // scalar RMW into ring slot (each row owned by exactly one lane)
                trp[st * RDIM + rowA] += dA;
                if (sub == 0) trp[st * RDIM + rowB] += dd[4];
            }
            tap_base += CHUNK_B; if (tap_base >= RING_B) tap_base -= RING_B;
        }
        // LDS-only fence + raw barrier: do NOT drain vmcnt (global stores in flight)
        asm volatile("s_waitcnt lgkmcnt(0)" ::: "memory");
        __builtin_amdgcn_s_barrier();
    }
}

extern "C" void kernel_launch(void* const* d_in, const int* in_sizes, int n_in,
                              void* d_out, int out_size, void* d_ws, size_t ws_size,
                              hipStream_t stream) {
    const float* x    = (const float*)d_in[0];   // (64, 8192, 1)
    const float* W_in = (const float*)d_in[1];   // (80, 1)
    const float* W_fb = (const float*)d_in[2];   // (5, 80, 80)
    const float* bias = (const float*)d_in[3];   // (80,)
    float* out        = (float*)d_out;           // (64, 8192, 80)

    reservoir_kernel<<<BATCH, 256, 0, stream>>>(x, W_in, W_fb, bias, out);
}

// Round 10
// 3377.257 us; speedup vs baseline: 1.4455x; 1.4455x over previous
//
#include <hip/hip_runtime.h>

#define BATCH 64
#define SEQ 8192
#define RDIM 80
#define RING 169              // max delay 168 + 1
#define NCHUNK (SEQ / 2)      // 2 steps per chunk, 1 barrier per chunk
#define SLOT_B (RDIM * 4)            // 320 B per ring slot
#define RING_B (RING * RDIM * 4)     // 54080 B

typedef float v2f __attribute__((ext_vector_type(2)));

__device__ __forceinline__ float fast_tanh(float z) {
    // tanh(z) = 1 - 2/(exp(2z)+1); exact saturation, abs err ~1e-7
    float e = __expf(2.0f * z);
    return 1.0f - 2.0f / (e + 1.0f);
}

// v + (v from lane ^ pattern) via DPP quad_perm (pure VALU, no LDS/SGPR hazard)
// 0xB1 = quad_perm(1,0,3,2) -> xor 1 ; 0x4E = quad_perm(2,3,0,1) -> xor 2
template <int CTRL>
__device__ __forceinline__ float dpp_xor_add(float v) {
    int o = __builtin_amdgcn_mov_dpp(__float_as_int(v), CTRL, 0xF, 0xF, true);
    return v + __int_as_float(o);
}

// R3 structure (best known: single batch/block, 4 waves, 1 wave/SIMD, 2-step
// chunks). This round strips REC-side overhead only (rec is the proven critical
// path: R2->R3 tap-work doubling was free; R9 rec-work doubling cost 45%):
//  - no per-step exec-mask divergence: all quad lanes compute hB redundantly
//    (dd[4] is already all-reduced; rgB/bB/winB are quad-uniform); LDS/global
//    writes of hB are same-address-same-value from 4 lanes -> legal, one wins.
//  - incremental ring byte offsets (no % per chunk)
//  - float4 readback reinterpreted as v2f (no repack moves)
__global__ __attribute__((amdgpu_flat_work_group_size(256, 256),
                          amdgpu_waves_per_eu(1, 1)))
void reservoir_kernel(const float* __restrict__ x,
                      const float* __restrict__ W_in,
                      const float* __restrict__ W_fb,
                      const float* __restrict__ bias,
                      float* __restrict__ out) {
    // ring[slot][i]: accumulated far-tap contributions for step s = slot (mod 169)
    __shared__ __align__(16) float ring[RING * RDIM];    // 54080 B
    // h_hist[s&3][i]: h for step s; rec wave writes, taps + rec-broadcast read
    __shared__ __align__(16) float h_hist[4 * RDIM];     // 1280 B

    const int b    = blockIdx.x;
    const int t    = threadIdx.x;
    const int wid  = t >> 6;   // 0 = recurrence, 1..3 = taps (one SIMD each)
    const int lane = t & 63;

    for (int i = t; i < RING * RDIM; i += 256) ring[i] = 0.0f;
    for (int i = t; i < 4 * RDIM; i += 256) h_hist[i] = 0.0f;

    const float* xb   = x + (size_t)b * SEQ;
    float*       outb = out + (size_t)b * (size_t)SEQ * RDIM;

    v2f wr2[80];   // per-lane weight slice as packed pairs (rec uses first 50)

    // ---- rec layout: quad q owns rows 5q..5q+4; lane (q,sub) covers j in [20*sub, 20*sub+20)
    int q = 0, sub = 0, rowA = 0, rowB = 0;
    float hA = 0.f, hB = 0.f, winA = 0.f, winB = 0.f, bA = 0.f, bB = 0.f;
    float4 hh4[5];   // rec: broadcast h_{s-1} slice, carried across steps
    int off0 = 0;    // rec: byte offset of ring slot for step 2c (incremental)
    // ---- tap layout (waves 1..3, both steps of the chunk) — UNCHANGED from R3:
    //      unit g = (wid-1)*64+lane < 160 ; k=g/40 -> tau{4,24,96,168};
    //      qq=(g%40)/2 -> rows 4qq..4qq+3 ; half=g&1 -> j in [40*half, 40*half+40)
    int tap_tau = 0, qq = 0, half = 0;
    bool tap_valid = false, tap_lo = false;
    float x0 = 0.f, x1 = 0.f;

    if (wid == 0) {
        q = lane >> 2; sub = lane & 3;
        rowA = 5 * q + sub;        // owned by this lane
        rowB = 5 * q + 4;          // shared by the quad (computed redundantly)
        #pragma unroll
        for (int r = 0; r < 5; ++r) {
            const float* src = W_fb + (size_t)(5 * q + r) * RDIM + 20 * sub;  // W_1 rows
            #pragma unroll
            for (int j4 = 0; j4 < 5; ++j4) {
                float4 v = ((const float4*)src)[j4];
                wr2[r * 10 + 2 * j4 + 0] = (v2f){v.x, v.y};
                wr2[r * 10 + 2 * j4 + 1] = (v2f){v.z, v.w};
            }
        }
        winA = W_in[rowA]; bA = bias[rowA];
        winB = W_in[rowB]; bB = bias[rowB];
        #pragma unroll
        for (int j4 = 0; j4 < 5; ++j4) hh4[j4] = (float4){0.f, 0.f, 0.f, 0.f};  // h_{-1}=0
        x0 = xb[0]; x1 = xb[1];
    } else {
        int g = (wid - 1) * 64 + lane;
        tap_valid = (g < 160);
        int gg = tap_valid ? g : 159;
        int k = gg / 40, rem = gg % 40;
        qq = rem >> 1; half = rem & 1;
        tap_lo = (half == 0);
        const int taus[4] = {4, 24, 96, 168};
        tap_tau = taus[k];
        #pragma unroll
        for (int r = 0; r < 4; ++r) {
            const float* src = W_fb + (size_t)(k + 1) * RDIM * RDIM
                                    + (size_t)(4 * qq + r) * RDIM + 40 * half;
            #pragma unroll
            for (int j4 = 0; j4 < 10; ++j4) {
                float4 v = ((const float4*)src)[j4];
                wr2[r * 20 + 2 * j4 + 0] = (v2f){v.x, v.y};
                wr2[r * 20 + 2 * j4 + 1] = (v2f){v.z, v.w};
            }
        }
    }

    __syncthreads();   // full fence once; in-loop barriers are raw s_barrier

    for (int c = 0; c < NCHUNK; ++c) {
        if (wid == 0) {
            // ================= recurrence wave: steps 2c, 2c+1 =================
            const int s0 = 2 * c;
            int off1 = off0 + SLOT_B; if (off1 >= RING_B) off1 -= RING_B;
            float* p0 = (float*)((char*)ring + off0);
            float* p1 = (float*)((char*)ring + off1);
            // ring slots for this chunk are final (taps this chunk write slots >= 2c+2).
            // rgB/zero of rowB: 4 quad lanes, same address (broadcast read / one-wins write)
            float rgA0 = p0[rowA], rgA1 = p1[rowA];
            float rgB0 = p0[rowB], rgB1 = p1[rowB];
            p0[rowA] = 0.f; p1[rowA] = 0.f;
            p0[rowB] = 0.f; p1[rowB] = 0.f;
            off0 += 2 * SLOT_B; if (off0 >= RING_B) off0 -= RING_B;
            // prefetch next chunk's x (8B aligned: s0+2 even)
            float xn0 = x0, xn1 = x1;
            if (s0 + 2 < SEQ) { float2 xn = *(const float2*)(xb + s0 + 2); xn0 = xn.x; xn1 = xn.y; }

            #pragma unroll
            for (int st = 0; st < 2; ++st) {
                const int s     = s0 + st;
                const float xs  = st ? x1   : x0;
                const float rgA = st ? rgA1 : rgA0;
                const float rgB = st ? rgB1 : rgB0;
                // hh4 already holds the broadcast h_{s-1} slice (readback last step)
                const v2f* hv = (const v2f*)hh4;
                v2f dd2[5];
                #pragma unroll
                for (int r = 0; r < 5; ++r) dd2[r] = (v2f){0.f, 0.f};
                #pragma unroll
                for (int r = 0; r < 5; ++r)
                    #pragma unroll
                    for (int j2 = 0; j2 < 10; ++j2)
                        dd2[r] = __builtin_elementwise_fma(wr2[r * 10 + j2], hv[j2], dd2[r]);
                float dd[5];
                #pragma unroll
                for (int r = 0; r < 5; ++r) dd[r] = dd2[r].x + dd2[r].y;
                // quad all-reduce: every lane gets full dots for its quad's 5 rows
                #pragma unroll
                for (int r = 0; r < 5; ++r) {
                    dd[r] = dpp_xor_add<0xB1>(dd[r]);
                    dd[r] = dpp_xor_add<0x4E>(dd[r]);
                }
                float dA = (sub == 0) ? dd[0] : (sub == 1) ? dd[1] : (sub == 2) ? dd[2] : dd[3];
                float zA = dA + rgA + bA + xs * winA;
                hA = 0.7f * hA + 0.3f * fast_tanh(zA);
                // hB computed UNIFORMLY by all 4 quad lanes (no exec-mask toggle)
                float zB = dd[4] + rgB + bB + xs * winB;
                hB = 0.7f * hB + 0.3f * fast_tanh(zB);
                // publish h_s (rowB: 4 lanes, same address, same value — one wins)
                h_hist[(s & 3) * RDIM + rowA] = hA;
                h_hist[(s & 3) * RDIM + rowB] = hB;
                // immediately read back the broadcast slice for step s+1
                // (same-wave DS ordering; only this wave writes h_hist)
                {
                    const float4* hp = (const float4*)(h_hist + (s & 3) * RDIM + 20 * sub);
                    #pragma unroll
                    for (int j4 = 0; j4 < 5; ++j4) hh4[j4] = hp[j4];
                }
                // fire-and-forget output stores (never read; no vmcnt drain);
                // rowB store: 4 lanes same addr+value — legal, coalescer merges
                outb[(size_t)s * RDIM + rowA] = hA;
                outb[(size_t)s * RDIM + rowB] = hB;
            }
            x0 = xn0; x1 = xn1;
        } else if (c > 0) {
            // ===== tap waves (UNCHANGED R3 body): steps 2(c-1), 2(c-1)+1 =====
            const int sp0 = 2 * (c - 1);
            #pragma unroll
            for (int st = 0; st < 2; ++st) {
                const int sp = sp0 + st;
                const float* hp = h_hist + (sp & 3) * RDIM + 40 * half;
                v2f ha2[20];
                #pragma unroll
                for (int j4 = 0; j4 < 10; ++j4) {
                    float4 v = ((const float4*)hp)[j4];
                    ha2[2 * j4 + 0] = (v2f){v.x, v.y};
                    ha2[2 * j4 + 1] = (v2f){v.z, v.w};
                }
                v2f dA2[4];
                #pragma unroll
                for (int r = 0; r < 4; ++r) dA2[r] = (v2f){0.f, 0.f};
                #pragma unroll
                for (int r = 0; r < 4; ++r)
                    #pragma unroll
                    for (int j2 = 0; j2 < 20; ++j2)
                        dA2[r] = __builtin_elementwise_fma(wr2[r * 20 + j2], ha2[j2], dA2[r]);
                float dA[4];
                #pragma unroll
                for (int r = 0; r < 4; ++r) dA[r] = dA2[r].x + dA2[r].y;
                // combine j-halves across the (even,odd) lane pair
                #pragma unroll
                for (int r = 0; r < 4; ++r)
                    dA[r] = dpp_xor_add<0xB1>(dA[r]);
                if (tap_valid && tap_lo) {
                    const int sl = (sp + tap_tau) % RING;
                    float4* pA = (float4*)(ring + sl * RDIM + 4 * qq);
                    float4 vA = *pA;
                    vA.x += dA[0]; vA.y += dA[1]; vA.z += dA[2]; vA.w += dA[3];
                    *pA = vA;
                }
            }
        }
        // LDS-only fence + raw barrier: do NOT drain vmcnt (global stores in flight)
        asm volatile("s_waitcnt lgkmcnt(0)" ::: "memory");
        __builtin_amdgcn_s_barrier();
    }
}

extern "C" void kernel_launch(void* const* d_in, const int* in_sizes, int n_in,
                              void* d_out, int out_size, void* d_ws, size_t ws_size,
                              hipStream_t stream) {
    const float* x    = (const float*)d_in[0];   // (64, 8192, 1)
    const float* W_in = (const float*)d_in[1];   // (80, 1)
    const float* W_fb = (const float*)d_in[2];   // (5, 80, 80)
    const float* bias = (const float*)d_in[3];   // (80,)
    float* out        = (float*)d_out;           // (64, 8192, 80)

    reservoir_kernel<<<BATCH, 256, 0, stream>>>(x, W_in, W_fb, bias, out);
}